// Round 16
// baseline (508.081 us; speedup 1.0000x reference)
//
#include <hip/hip_runtime.h>
#include <hip/hip_bf16.h>

// Transducer joint: logits[b,t,u,v] = tanh(enc_proj[b,t,:]+dec_proj[b,u,:]+b1) @ W2 + b2
// B=4 T=256 U=128, ENC=DEC=512, INNER=512, VOCAB=2048
// R16 = R15 (tanh fused into BM=128 BN=256 BK=32 ring-3 GEMM, plain 1KB
// epilogue stores) + FIX: barrier between the encl LDS write and the prologue
// TANHW reads (cross-wave visibility race caused absmax 0.37).

typedef __attribute__((ext_vector_type(4))) float f32x4;
typedef __attribute__((ext_vector_type(8))) __bf16 bf16x8;
typedef __attribute__((ext_vector_type(8))) unsigned short u16x8;
typedef __attribute__((ext_vector_type(4))) unsigned int u32x4;

__device__ __forceinline__ float bf2f(unsigned short u) {
  unsigned int x = ((unsigned int)u) << 16;
  return __builtin_bit_cast(float, x);
}
__device__ __forceinline__ unsigned short f2bf(float f) {
  unsigned int x = __builtin_bit_cast(unsigned int, f);
  x += 0x7fff + ((x >> 16) & 1);   // RNE
  return (unsigned short)(x >> 16);
}
__device__ __forceinline__ float tanh_fast(float x) {
  float e = __expf(2.0f * x);
  return 1.0f - 2.0f * __builtin_amdgcn_rcpf(e + 1.0f);
}
// packed RNE f32x2 -> 2xbf16 in a u32
__device__ __forceinline__ unsigned int pk2bf(float lo, float hi) {
  return (unsigned int)f2bf(lo) | ((unsigned int)f2bf(hi) << 16);
}

typedef __attribute__((address_space(3))) unsigned int lds_u32;
typedef const __attribute__((address_space(1))) unsigned int glb_u32;
__device__ __forceinline__ void gl16(const void* g, void* l) {
  __builtin_amdgcn_global_load_lds((glb_u32*)g, (lds_u32*)l, 16, 0, 0);
}

#define BAR __builtin_amdgcn_s_barrier()
#define LGKM0 asm volatile("s_waitcnt lgkmcnt(0)" ::: "memory")
#define VMCNT(n) asm volatile("s_waitcnt vmcnt(" #n ")" ::: "memory")
#define MEMPIN asm volatile("" ::: "memory")

// ---------------- Pass 1: proj (x-in-LDS broadcast GEMM) ----------------
__global__ __launch_bounds__(512) void proj8_kernel(
    const float* __restrict__ enc, const float* __restrict__ dec,
    const float* __restrict__ W1, const float* __restrict__ b1,
    float* __restrict__ enc_proj, unsigned short* __restrict__ decb) {
  __shared__ float xs[8][512];
  const int bid = blockIdx.x;
  const bool isenc = bid < 128;
  const int rows0 = (isenc ? bid : bid - 128) * 8;
  const float* src = (isenc ? enc : dec) + (size_t)rows0 * 512;
  const int tid = threadIdx.x;
#pragma unroll
  for (int j = 0; j < 2; ++j) {
    int v = j * 512 + tid;
    int row = v >> 7;
    int c4 = (v & 127) << 2;
    *(f32x4*)&xs[row][c4] = *(const f32x4*)&src[(size_t)row * 512 + c4];
  }
  __syncthreads();
  const int h = tid;
  const float* wp = W1 + (isenc ? 0 : (size_t)512 * 512) + h;
  float acc[8];
  float init = isenc ? 0.f : b1[h];
#pragma unroll
  for (int r = 0; r < 8; ++r) acc[r] = init;
#pragma unroll 4
  for (int k = 0; k < 512; ++k) {
    float wv = wp[(size_t)k * 512];
#pragma unroll
    for (int r = 0; r < 8; ++r) acc[r] = fmaf(xs[r][k], wv, acc[r]);
  }
  if (isenc) {
#pragma unroll
    for (int r = 0; r < 8; ++r) enc_proj[(size_t)(rows0 + r) * 512 + h] = acc[r];
  } else {
#pragma unroll
    for (int r = 0; r < 8; ++r) decb[(size_t)(rows0 + r) * 512 + h] = f2bf(acc[r]);
  }
}

// ---------------- Pass 2: W2 [512][2048] fp32 -> W2t [2048][512] bf16 ----------------
__global__ __launch_bounds__(256) void w2t_kernel(const float* __restrict__ W2,
                                                  unsigned short* __restrict__ W2t) {
  __shared__ unsigned short tile[32][33];
  int bn = blockIdx.x;
  int bk = blockIdx.y;
  int tx = threadIdx.x & 31;
  int ty = threadIdx.x >> 5;
#pragma unroll
  for (int i = 0; i < 32; i += 8)
    tile[ty + i][tx] = f2bf(W2[(size_t)(bk * 32 + ty + i) * 2048 + bn * 32 + tx]);
  __syncthreads();
#pragma unroll
  for (int i = 0; i < 32; i += 8)
    W2t[(size_t)(bn * 32 + ty + i) * 512 + bk * 32 + tx] = tile[tx][ty + i];
}

// ---------------- Pass 3: fused tanh-GEMM, BM=128 BN=256 BK=32 ----------------
// LDS: ring 3 x 24576 (A [128][32] 8KB @0 + B [256][32] 16KB @8192) + enc row
// 2048B = 75776 -> 2 blocks/CU. 8 waves (2M x 4N), wave-tile 64x64.
// Per phase t: VMCNT(2); BAR; frag ds_reads (slot t%3); issue dec(t+3)->reg;
// issue gl16 B(t+2); 16 MFMA; tanh A(t+2) from dec(t+2) regs + enc LDS,
// ds_write (0-conflict swizzle) into slot (t+2)%3; LGKM0.
// Epilogue: 8 chunks of 16 rows via LDS [16][260] f32; 1KB plain stores.

__global__ __launch_bounds__(512, 4) void gemmft_kernel(
    const float* __restrict__ encp,           // [1024][512] f32
    const unsigned short* __restrict__ decb,  // [512][512] bf16 (b1 folded)
    const unsigned short* __restrict__ W2t,   // [2048][512] bf16
    const float* __restrict__ b2,             // [2048]
    float* __restrict__ out) {                // [131072][2048] fp32
  __shared__ __align__(1024) char smem[75776];

  const int bid = blockIdx.x;
  const int wg = (bid & 7) * 1024 + (bid >> 3);  // 8192%8==0 -> bijective
  const int my = wg >> 3;    // 0..1023 = bt (A panel = one (b,t) row x 128 u)
  const int ny = wg & 7;     // 0..7 (256-col block)

  const int tid = threadIdx.x;
  const int lane = tid & 63;
  const int w = tid >> 6;    // 0..7
  const int wm = w >> 2;     // 0..1
  const int wn = w & 3;      // 0..3
  const int fr = lane & 15;
  const int fq = lane >> 4;

  // ---- B staging (gl16, linear dest, pre-swizzled src) ----
  size_t srcB[2];
#pragma unroll
  for (int p = 0; p < 2; ++p) {
    int d = p * 8192 + w * 1024 + lane * 16;   // within 16KB B region
    int r = d >> 6;                            // row 0..255
    int c = (d >> 4) & 3;
    srcB[p] = (size_t)r * 1024 + (size_t)((c ^ ((r >> 1) & 3)) << 4);
  }
  const char* wb = (const char*)(W2t + (size_t)ny * 256 * 512);

  // ---- A tanh-write address (same swizzle as reads) ----
  const int arow = tid >> 2;                   // 0..127 (u)
  const int achk = tid & 3;                    // 16B chunk
  const int aoff = arow * 64 + ((achk ^ ((arow >> 1) & 3)) << 4);
  const unsigned short* dp =
      decb + ((size_t)((my >> 8) * 128 + arow)) * 512 + achk * 8;

  // enc row in LDS
  float* encl = (float*)(smem + 73728);
  if (tid < 128)
    *(f32x4*)&encl[tid * 4] = *(const f32x4*)&encp[(size_t)my * 512 + tid * 4];

  // frag read offsets
  const int swz = (fq ^ ((fr >> 1) & 3)) << 4;
  const int ldsA = (wm * 64 + fr) * 64 + swz;          // + mi*1024
  const int ldsB = 8192 + (wn * 64 + fr) * 64 + swz;   // + ni*1024

  f32x4 acc[4][4];
#pragma unroll
  for (int i = 0; i < 4; ++i)
#pragma unroll
    for (int j = 0; j < 4; ++j) acc[i][j] = (f32x4){0.f, 0.f, 0.f, 0.f};

#define STAGEB(tt, slot)                                        \
  do {                                                          \
    char* sl = smem + (slot)*24576;                             \
    gl16(wb + srcB[0] + (tt)*64, sl + 8192 + w * 1024);         \
    gl16(wb + srcB[1] + (tt)*64, sl + 16384 + w * 1024);        \
  } while (0)

// compute tanh A(slice s) from dv (u16x8 dec regs) and enc LDS; swizzled write
#define TANHW(s, dv)                                                        \
  do {                                                                      \
    f32x4 e0 = *(const f32x4*)&encl[(s)*32 + achk * 8];                     \
    f32x4 e1 = *(const f32x4*)&encl[(s)*32 + achk * 8 + 4];                 \
    float f[8];                                                             \
    _Pragma("unroll") for (int j = 0; j < 4; ++j)                           \
        f[j] = tanh_fast(bf2f((dv)[j]) + e0[j]);                            \
    _Pragma("unroll") for (int j = 0; j < 4; ++j)                           \
        f[4 + j] = tanh_fast(bf2f((dv)[4 + j]) + e1[j]);                    \
    u32x4 pk;                                                               \
    _Pragma("unroll") for (int j = 0; j < 4; ++j)                           \
        pk[j] = pk2bf(f[2 * j], f[2 * j + 1]);                              \
    *(u32x4*)(smem + ((s) % 3) * 24576 + aoff) = pk;                        \
  } while (0)

  // ---- prologue ----
  STAGEB(0, 0);
  STAGEB(1, 1);
  LGKM0;        // own encl ds_write drained...
  BAR; MEMPIN;  // ...and visible block-wide before any TANHW reads encl
  {
    u16x8 d0 = *(const u16x8*)(dp);            // dec slice 0
    u16x8 d1 = *(const u16x8*)(dp + 32);       // dec slice 1
    MEMPIN;
    TANHW(0, d0);
    TANHW(1, d1);
  }
  u16x8 decreg[2];
  decreg[0] = *(const u16x8*)(dp + 2 * 32);    // dec slice 2
  MEMPIN;
  VMCNT(0);     // gl16 B0,B1 landed (dec loads drained too; one-time cost)
  LGKM0;
  BAR; MEMPIN;

  // ---- 16 phases ----
#pragma unroll
  for (int t = 0; t < 16; ++t) {
    if (t > 0) {                 // phase-0 gate handled by prologue VMCNT(0)
      if (t < 15) { VMCNT(2); } else { VMCNT(0); }
      BAR; MEMPIN;
    }
    const char* As = smem + (t % 3) * 24576;
    bf16x8 a4[4], b4[4];
#pragma unroll
    for (int mi = 0; mi < 4; ++mi) a4[mi] = *(const bf16x8*)(As + ldsA + mi * 1024);
#pragma unroll
    for (int ni = 0; ni < 4; ++ni) b4[ni] = *(const bf16x8*)(As + ldsB + ni * 1024);

    if (t <= 12) decreg[(t + 1) & 1] = *(const u16x8*)(dp + (t + 3) * 32);
    MEMPIN;
    if (t <= 13) STAGEB(t + 2, (t + 2) % 3);
    MEMPIN;

    __builtin_amdgcn_s_setprio(1);
#pragma unroll
    for (int mi = 0; mi < 4; ++mi)
#pragma unroll
      for (int ni = 0; ni < 4; ++ni)
        acc[mi][ni] = __builtin_amdgcn_mfma_f32_16x16x32_bf16(
            a4[mi], b4[ni], acc[mi][ni], 0, 0, 0);
    __builtin_amdgcn_s_setprio(0);

    if (t <= 13) TANHW(t + 2, decreg[t & 1]);   // A for slice t+2 -> slot (t+2)%3
    LGKM0;
    if (t == 15) { BAR; MEMPIN; }
  }

  // ---- epilogue: 8 chunks of 16 rows; 1KB-contiguous PLAIN stores ----
  float* lbuf = (float*)smem;                 // [16][260] f32
  const size_t orow0 = (size_t)my * 128;
  const int ncol0 = ny * 256;
  float bvv[4];
#pragma unroll
  for (int ni = 0; ni < 4; ++ni) bvv[ni] = b2[ncol0 + wn * 64 + ni * 16 + fr];

#pragma unroll
  for (int c = 0; c < 8; ++c) {
    if ((c >> 2) == wm) {                     // 4 producer waves per chunk
      const int mi = c & 3;
#pragma unroll
      for (int ni = 0; ni < 4; ++ni)
#pragma unroll
        for (int r = 0; r < 4; ++r)
          lbuf[(fq * 4 + r) * 260 + wn * 64 + ni * 16 + fr] =
              acc[mi][ni][r] + bvv[ni];
    }
    LGKM0; BAR; MEMPIN;
#pragma unroll
    for (int rr = 0; rr < 2; ++rr) {
      const int row = w * 2 + rr;
      f32x4 v = *(const f32x4*)&lbuf[row * 260 + lane * 4];
      *(f32x4*)&out[(orow0 + c * 16 + row) * 2048 + ncol0 + lane * 4] = v;
    }
    LGKM0; BAR; MEMPIN;
  }
#undef STAGEB
#undef TANHW
}

extern "C" void kernel_launch(void* const* d_in, const int* in_sizes, int n_in,
                              void* d_out, int out_size, void* d_ws, size_t ws_size,
                              hipStream_t stream) {
  const float* enc = (const float*)d_in[0];
  const float* dec = (const float*)d_in[1];
  const float* W1  = (const float*)d_in[2];
  const float* b1  = (const float*)d_in[3];
  const float* W2  = (const float*)d_in[4];
  const float* b2  = (const float*)d_in[5];
  float* out = (float*)d_out;

  char* ws = (char*)d_ws;
  float* enc_proj = (float*)ws;                                    // 2 MB
  unsigned short* decb = (unsigned short*)(ws + (2u << 20));       // 512 KB
  unsigned short* W2t  = (unsigned short*)(ws + (2u << 20) + (512u << 10)); // 2 MB

  proj8_kernel<<<192, 512, 0, stream>>>(enc, dec, W1, b1, enc_proj, decb);
  w2t_kernel<<<dim3(64, 16), 256, 0, stream>>>(W2, W2t);
  gemmft_kernel<<<8192, 512, 0, stream>>>(enc_proj, decb, W2t, b2, out);
}

// Round 17
// 461.830 us; speedup vs baseline: 1.1001x; 1.1001x over previous
//
#include <hip/hip_runtime.h>
#include <hip/hip_bf16.h>

// Transducer joint: logits[b,t,u,v] = tanh(enc_proj[b,t,:]+dec_proj[b,u,:]+b1) @ W2 + b2
// B=4 T=256 U=128, ENC=DEC=512, INNER=512, VOCAB=2048
// R17 = R16 (fused tanh-GEMM, passed @508us) with ONE change: epilogue stores
// plain -> nontemporal (A/B across the store-flavor matrix: nt is worth
// ~-140us in this GEMM; R13 de-fused+nt=398.7, R16 fused+plain=508).

typedef __attribute__((ext_vector_type(4))) float f32x4;
typedef __attribute__((ext_vector_type(8))) __bf16 bf16x8;
typedef __attribute__((ext_vector_type(8))) unsigned short u16x8;
typedef __attribute__((ext_vector_type(4))) unsigned int u32x4;

__device__ __forceinline__ float bf2f(unsigned short u) {
  unsigned int x = ((unsigned int)u) << 16;
  return __builtin_bit_cast(float, x);
}
__device__ __forceinline__ unsigned short f2bf(float f) {
  unsigned int x = __builtin_bit_cast(unsigned int, f);
  x += 0x7fff + ((x >> 16) & 1);   // RNE
  return (unsigned short)(x >> 16);
}
__device__ __forceinline__ float tanh_fast(float x) {
  float e = __expf(2.0f * x);
  return 1.0f - 2.0f * __builtin_amdgcn_rcpf(e + 1.0f);
}
// packed RNE f32x2 -> 2xbf16 in a u32
__device__ __forceinline__ unsigned int pk2bf(float lo, float hi) {
  return (unsigned int)f2bf(lo) | ((unsigned int)f2bf(hi) << 16);
}

typedef __attribute__((address_space(3))) unsigned int lds_u32;
typedef const __attribute__((address_space(1))) unsigned int glb_u32;
__device__ __forceinline__ void gl16(const void* g, void* l) {
  __builtin_amdgcn_global_load_lds((glb_u32*)g, (lds_u32*)l, 16, 0, 0);
}

#define BAR __builtin_amdgcn_s_barrier()
#define LGKM0 asm volatile("s_waitcnt lgkmcnt(0)" ::: "memory")
#define VMCNT(n) asm volatile("s_waitcnt vmcnt(" #n ")" ::: "memory")
#define MEMPIN asm volatile("" ::: "memory")

// ---------------- Pass 1: proj (x-in-LDS broadcast GEMM) ----------------
__global__ __launch_bounds__(512) void proj8_kernel(
    const float* __restrict__ enc, const float* __restrict__ dec,
    const float* __restrict__ W1, const float* __restrict__ b1,
    float* __restrict__ enc_proj, unsigned short* __restrict__ decb) {
  __shared__ float xs[8][512];
  const int bid = blockIdx.x;
  const bool isenc = bid < 128;
  const int rows0 = (isenc ? bid : bid - 128) * 8;
  const float* src = (isenc ? enc : dec) + (size_t)rows0 * 512;
  const int tid = threadIdx.x;
#pragma unroll
  for (int j = 0; j < 2; ++j) {
    int v = j * 512 + tid;
    int row = v >> 7;
    int c4 = (v & 127) << 2;
    *(f32x4*)&xs[row][c4] = *(const f32x4*)&src[(size_t)row * 512 + c4];
  }
  __syncthreads();
  const int h = tid;
  const float* wp = W1 + (isenc ? 0 : (size_t)512 * 512) + h;
  float acc[8];
  float init = isenc ? 0.f : b1[h];
#pragma unroll
  for (int r = 0; r < 8; ++r) acc[r] = init;
#pragma unroll 4
  for (int k = 0; k < 512; ++k) {
    float wv = wp[(size_t)k * 512];
#pragma unroll
    for (int r = 0; r < 8; ++r) acc[r] = fmaf(xs[r][k], wv, acc[r]);
  }
  if (isenc) {
#pragma unroll
    for (int r = 0; r < 8; ++r) enc_proj[(size_t)(rows0 + r) * 512 + h] = acc[r];
  } else {
#pragma unroll
    for (int r = 0; r < 8; ++r) decb[(size_t)(rows0 + r) * 512 + h] = f2bf(acc[r]);
  }
}

// ---------------- Pass 2: W2 [512][2048] fp32 -> W2t [2048][512] bf16 ----------------
__global__ __launch_bounds__(256) void w2t_kernel(const float* __restrict__ W2,
                                                  unsigned short* __restrict__ W2t) {
  __shared__ unsigned short tile[32][33];
  int bn = blockIdx.x;
  int bk = blockIdx.y;
  int tx = threadIdx.x & 31;
  int ty = threadIdx.x >> 5;
#pragma unroll
  for (int i = 0; i < 32; i += 8)
    tile[ty + i][tx] = f2bf(W2[(size_t)(bk * 32 + ty + i) * 2048 + bn * 32 + tx]);
  __syncthreads();
#pragma unroll
  for (int i = 0; i < 32; i += 8)
    W2t[(size_t)(bn * 32 + ty + i) * 512 + bk * 32 + tx] = tile[tx][ty + i];
}

// ---------------- Pass 3: fused tanh-GEMM, BM=128 BN=256 BK=32 ----------------
// LDS: ring 3 x 24576 (A [128][32] 8KB @0 + B [256][32] 16KB @8192) + enc row
// 2048B = 75776 -> 2 blocks/CU. 8 waves (2M x 4N), wave-tile 64x64.
// Per phase t: VMCNT(2); BAR; frag ds_reads (slot t%3); issue dec(t+3)->reg;
// issue gl16 B(t+2); 16 MFMA; tanh A(t+2) from dec(t+2) regs + enc LDS,
// ds_write (0-conflict swizzle) into slot (t+2)%3; LGKM0.
// Epilogue: 8 chunks of 16 rows via LDS [16][260] f32; 1KB nt stores.

__global__ __launch_bounds__(512, 4) void gemmft_kernel(
    const float* __restrict__ encp,           // [1024][512] f32
    const unsigned short* __restrict__ decb,  // [512][512] bf16 (b1 folded)
    const unsigned short* __restrict__ W2t,   // [2048][512] bf16
    const float* __restrict__ b2,             // [2048]
    float* __restrict__ out) {                // [131072][2048] fp32
  __shared__ __align__(1024) char smem[75776];

  const int bid = blockIdx.x;
  const int wg = (bid & 7) * 1024 + (bid >> 3);  // 8192%8==0 -> bijective
  const int my = wg >> 3;    // 0..1023 = bt (A panel = one (b,t) row x 128 u)
  const int ny = wg & 7;     // 0..7 (256-col block)

  const int tid = threadIdx.x;
  const int lane = tid & 63;
  const int w = tid >> 6;    // 0..7
  const int wm = w >> 2;     // 0..1
  const int wn = w & 3;      // 0..3
  const int fr = lane & 15;
  const int fq = lane >> 4;

  // ---- B staging (gl16, linear dest, pre-swizzled src) ----
  size_t srcB[2];
#pragma unroll
  for (int p = 0; p < 2; ++p) {
    int d = p * 8192 + w * 1024 + lane * 16;   // within 16KB B region
    int r = d >> 6;                            // row 0..255
    int c = (d >> 4) & 3;
    srcB[p] = (size_t)r * 1024 + (size_t)((c ^ ((r >> 1) & 3)) << 4);
  }
  const char* wb = (const char*)(W2t + (size_t)ny * 256 * 512);

  // ---- A tanh-write address (same swizzle as reads) ----
  const int arow = tid >> 2;                   // 0..127 (u)
  const int achk = tid & 3;                    // 16B chunk
  const int aoff = arow * 64 + ((achk ^ ((arow >> 1) & 3)) << 4);
  const unsigned short* dp =
      decb + ((size_t)((my >> 8) * 128 + arow)) * 512 + achk * 8;

  // enc row in LDS
  float* encl = (float*)(smem + 73728);
  if (tid < 128)
    *(f32x4*)&encl[tid * 4] = *(const f32x4*)&encp[(size_t)my * 512 + tid * 4];

  // frag read offsets
  const int swz = (fq ^ ((fr >> 1) & 3)) << 4;
  const int ldsA = (wm * 64 + fr) * 64 + swz;          // + mi*1024
  const int ldsB = 8192 + (wn * 64 + fr) * 64 + swz;   // + ni*1024

  f32x4 acc[4][4];
#pragma unroll
  for (int i = 0; i < 4; ++i)
#pragma unroll
    for (int j = 0; j < 4; ++j) acc[i][j] = (f32x4){0.f, 0.f, 0.f, 0.f};

#define STAGEB(tt, slot)                                        \
  do {                                                          \
    char* sl = smem + (slot)*24576;                             \
    gl16(wb + srcB[0] + (tt)*64, sl + 8192 + w * 1024);         \
    gl16(wb + srcB[1] + (tt)*64, sl + 16384 + w * 1024);        \
  } while (0)

// compute tanh A(slice s) from dv (u16x8 dec regs) and enc LDS; swizzled write
#define TANHW(s, dv)                                                        \
  do {                                                                      \
    f32x4 e0 = *(const f32x4*)&encl[(s)*32 + achk * 8];                     \
    f32x4 e1 = *(const f32x4*)&encl[(s)*32 + achk * 8 + 4];                 \
    float f[8];                                                             \
    _Pragma("unroll") for (int j = 0; j < 4; ++j)                           \
        f[j] = tanh_fast(bf2f((dv)[j]) + e0[j]);                            \
    _Pragma("unroll") for (int j = 0; j < 4; ++j)                           \
        f[4 + j] = tanh_fast(bf2f((dv)[4 + j]) + e1[j]);                    \
    u32x4 pk;                                                               \
    _Pragma("unroll") for (int j = 0; j < 4; ++j)                           \
        pk[j] = pk2bf(f[2 * j], f[2 * j + 1]);                              \
    *(u32x4*)(smem + ((s) % 3) * 24576 + aoff) = pk;                        \
  } while (0)

  // ---- prologue ----
  STAGEB(0, 0);
  STAGEB(1, 1);
  LGKM0;        // own encl ds_write drained...
  BAR; MEMPIN;  // ...and visible block-wide before any TANHW reads encl
  {
    u16x8 d0 = *(const u16x8*)(dp);            // dec slice 0
    u16x8 d1 = *(const u16x8*)(dp + 32);       // dec slice 1
    MEMPIN;
    TANHW(0, d0);
    TANHW(1, d1);
  }
  u16x8 decreg[2];
  decreg[0] = *(const u16x8*)(dp + 2 * 32);    // dec slice 2
  MEMPIN;
  VMCNT(0);     // gl16 B0,B1 landed (dec loads drained too; one-time cost)
  LGKM0;
  BAR; MEMPIN;

  // ---- 16 phases ----
#pragma unroll
  for (int t = 0; t < 16; ++t) {
    if (t > 0) {                 // phase-0 gate handled by prologue VMCNT(0)
      if (t < 15) { VMCNT(2); } else { VMCNT(0); }
      BAR; MEMPIN;
    }
    const char* As = smem + (t % 3) * 24576;
    bf16x8 a4[4], b4[4];
#pragma unroll
    for (int mi = 0; mi < 4; ++mi) a4[mi] = *(const bf16x8*)(As + ldsA + mi * 1024);
#pragma unroll
    for (int ni = 0; ni < 4; ++ni) b4[ni] = *(const bf16x8*)(As + ldsB + ni * 1024);

    if (t <= 12) decreg[(t + 1) & 1] = *(const u16x8*)(dp + (t + 3) * 32);
    MEMPIN;
    if (t <= 13) STAGEB(t + 2, (t + 2) % 3);
    MEMPIN;

    __builtin_amdgcn_s_setprio(1);
#pragma unroll
    for (int mi = 0; mi < 4; ++mi)
#pragma unroll
      for (int ni = 0; ni < 4; ++ni)
        acc[mi][ni] = __builtin_amdgcn_mfma_f32_16x16x32_bf16(
            a4[mi], b4[ni], acc[mi][ni], 0, 0, 0);
    __builtin_amdgcn_s_setprio(0);

    if (t <= 13) TANHW(t + 2, decreg[t & 1]);   // A for slice t+2 -> slot (t+2)%3
    LGKM0;
    if (t == 15) { BAR; MEMPIN; }
  }

  // ---- epilogue: 8 chunks of 16 rows; 1KB-contiguous NT stores ----
  float* lbuf = (float*)smem;                 // [16][260] f32
  const size_t orow0 = (size_t)my * 128;
  const int ncol0 = ny * 256;
  float bvv[4];
#pragma unroll
  for (int ni = 0; ni < 4; ++ni) bvv[ni] = b2[ncol0 + wn * 64 + ni * 16 + fr];

#pragma unroll
  for (int c = 0; c < 8; ++c) {
    if ((c >> 2) == wm) {                     // 4 producer waves per chunk
      const int mi = c & 3;
#pragma unroll
      for (int ni = 0; ni < 4; ++ni)
#pragma unroll
        for (int r = 0; r < 4; ++r)
          lbuf[(fq * 4 + r) * 260 + wn * 64 + ni * 16 + fr] =
              acc[mi][ni][r] + bvv[ni];
    }
    LGKM0; BAR; MEMPIN;
#pragma unroll
    for (int rr = 0; rr < 2; ++rr) {
      const int row = w * 2 + rr;
      f32x4 v = *(const f32x4*)&lbuf[row * 260 + lane * 4];
      __builtin_nontemporal_store(
          v, (f32x4*)&out[(orow0 + c * 16 + row) * 2048 + ncol0 + lane * 4]);
    }
    LGKM0; BAR; MEMPIN;
  }
#undef STAGEB
#undef TANHW
}

extern "C" void kernel_launch(void* const* d_in, const int* in_sizes, int n_in,
                              void* d_out, int out_size, void* d_ws, size_t ws_size,
                              hipStream_t stream) {
  const float* enc = (const float*)d_in[0];
  const float* dec = (const float*)d_in[1];
  const float* W1  = (const float*)d_in[2];
  const float* b1  = (const float*)d_in[3];
  const float* W2  = (const float*)d_in[4];
  const float* b2  = (const float*)d_in[5];
  float* out = (float*)d_out;

  char* ws = (char*)d_ws;
  float* enc_proj = (float*)ws;                                    // 2 MB
  unsigned short* decb = (unsigned short*)(ws + (2u << 20));       // 512 KB
  unsigned short* W2t  = (unsigned short*)(ws + (2u << 20) + (512u << 10)); // 2 MB

  proj8_kernel<<<192, 512, 0, stream>>>(enc, dec, W1, b1, enc_proj, decb);
  w2t_kernel<<<dim3(64, 16), 256, 0, stream>>>(W2, W2t);
  gemmft_kernel<<<8192, 512, 0, stream>>>(enc_proj, decb, W2t, b2, out);
}